// Round 6
// baseline (990.141 us; speedup 1.0000x reference)
//
#include <hip/hip_runtime.h>
#include <hip/hip_bf16.h>

typedef __bf16 bf16_t;
typedef __bf16 bf16x8 __attribute__((ext_vector_type(8)));
typedef float f32x4 __attribute__((ext_vector_type(4)));

// async global->LDS, 16B per lane, dest = wave-uniform base + lane*16
#define GLL16(gp, lp)                                                          \
    __builtin_amdgcn_global_load_lds(                                          \
        (const __attribute__((address_space(1))) void*)(gp),                   \
        (__attribute__((address_space(3))) void*)(lp), 16, 0, 0)

#define SBAR() __builtin_amdgcn_s_barrier()
#define SCHED0() __builtin_amdgcn_sched_barrier(0)
#define WAIT_VM0() asm volatile("s_waitcnt vmcnt(0)" ::: "memory")
#define MFMA_(d, a, b)                                                         \
    d = __builtin_amdgcn_mfma_f32_16x16x32_bf16(a, b, d, 0, 0, 0)

// ---------------- E8 lattice quantization (fp64 decisions) ----------------

__device__ __forceinline__ void nearest_D8_d(const double x[8], double f[8]) {
    double d[8];
    double fs = 0.0;
#pragma unroll
    for (int i = 0; i < 8; ++i) {
        f[i] = rint(x[i]);              // round-half-to-even == jnp.round
        d[i] = x[i] - f[i];
        fs += f[i];
    }
    long long s = (long long)fs;
    if (s & 1LL) {
        int idx = 0;
        double best = fabs(d[0]);
#pragma unroll
        for (int i = 1; i < 8; ++i) {
            double a = fabs(d[i]);
            if (a > best) { best = a; idx = i; }   // strict > : first max
        }
        f[idx] += (d[idx] >= 0.0) ? 1.0 : -1.0;
    }
}

__device__ __forceinline__ void e8_quantize_d(const double x[8], float q[8]) {
    double y0[8], y1[8], xs[8];
    nearest_D8_d(x, y0);
#pragma unroll
    for (int i = 0; i < 8; ++i) xs[i] = x[i] - 0.5;
    nearest_D8_d(xs, y1);
#pragma unroll
    for (int i = 0; i < 8; ++i) y1[i] += 0.5;
    double d0 = 0.0, d1 = 0.0;
#pragma unroll
    for (int i = 0; i < 8; ++i) {
        double a = x[i] - y0[i]; d0 += a * a;
        double b = x[i] - y1[i]; d1 += b * b;
    }
    bool take0 = (d0 <= d1);
#pragma unroll
    for (int i = 0; i < 8; ++i) q[i] = (float)(take0 ? y0[i] : y1[i]);
}

// fused: blocks [0,OUT) quantize weight rows; blocks [OUT, OUT+CB) cvt x->bf16
__global__ __launch_bounds__(256) void prep_kernel(
    const float* __restrict__ W, bf16_t* __restrict__ Q,
    float* __restrict__ scale, int IN, double sfd,
    const float* __restrict__ x, bf16_t* __restrict__ Xb, long long n8,
    int OUT, int CB)
{
    if (blockIdx.x >= (unsigned)OUT) {
        // ---- cvt part ----
        long long i = (long long)(blockIdx.x - OUT) * 256 + threadIdx.x;
        long long stride = (long long)CB * 256;
        for (; i < n8; i += stride) {
            float4 v0 = *(const float4*)(x + i * 8);
            float4 v1 = *(const float4*)(x + i * 8 + 4);
            bf16x8 o;
            o[0] = (bf16_t)v0.x; o[1] = (bf16_t)v0.y;
            o[2] = (bf16_t)v0.z; o[3] = (bf16_t)v0.w;
            o[4] = (bf16_t)v1.x; o[5] = (bf16_t)v1.y;
            o[6] = (bf16_t)v1.z; o[7] = (bf16_t)v1.w;
            *(bf16x8*)(Xb + i * 8) = o;
        }
        return;
    }
    // ---- quant part ----
    const int row  = blockIdx.x;
    const int t    = threadIdx.x;
    const int lane = t & 63, w = t >> 6;
    const float* wrow = W + (size_t)row * IN;

    double ss = 0.0;
    for (int i = t; i < (IN >> 2); i += 256) {
        float4 v = *(const float4*)(wrow + i * 4);
        double a = v.x, b = v.y, c = v.z, d = v.w;
        ss += a * a + b * b + c * c + d * d;
    }
#pragma unroll
    for (int m = 1; m < 64; m <<= 1) ss += __shfl_xor(ss, m);
    __shared__ double red[4];
    if (lane == 0) red[w] = ss;
    __syncthreads();
    double S   = (red[0] + red[1]) + (red[2] + red[3]);
    double nsd = fmax(sqrt(S), 1e-8);

    for (int b = t; b < (IN >> 3); b += 256) {
        const float* xp = wrow + b * 8;
        float4 v0 = *(const float4*)xp;
        float4 v1 = *(const float4*)(xp + 4);
        double xd[8] = {v0.x, v0.y, v0.z, v0.w, v1.x, v1.y, v1.z, v1.w};
        double xsd[8];
#pragma unroll
        for (int i = 0; i < 8; ++i) xsd[i] = (xd[i] / nsd) * sfd;
        float qf[8];
        e8_quantize_d(xsd, qf);
        bf16x8 o;
#pragma unroll
        for (int i = 0; i < 8; ++i) o[i] = (bf16_t)qf[i];
        *(bf16x8*)(Q + (size_t)row * IN + b * 8) = o;
    }
    if (t == 0) scale[row] = (float)(nsd / sfd);
}

// ---------------- GEMM: 256x256 tile, BK=64, 8 waves.
// ONE barrier per K-tile; every ds_read is issued >=1 window before its
// consuming MFMA (register-level pipelining), so LDS service hides under
// MFMA. W1{read b23,a1 | Q1} -> vmcnt(0)+BAR -> W2{Q2,Q3} ->
// W3{read next A0,b01 from other buf | stage kt+2 | Q4}.
// C[m,n] = (sum_k A[m,k]*B[n,k]) * scale[n] + bias[n].  Requires NT even.

#define BM 256
#define BN 256
#define BK 64

__global__ __launch_bounds__(512, 2) void gemm_kernel(
    const bf16_t* __restrict__ A,      // [M][K]
    const bf16_t* __restrict__ B,      // [N][K]
    const float* __restrict__ scale,   // [N]
    const float* __restrict__ bias,    // [N]
    float* __restrict__ C,             // [M][N]
    int M, int N, int K)
{
    // [buf][A=0/B=1][half][128 rows * 64 cols]  = 128 KiB
    __shared__ __align__(16) bf16_t lds[2][2][2][8192];

    const int t    = threadIdx.x;
    const int lane = t & 63;
    const int w    = t >> 6;          // 0..7
    const int wr   = w >> 2;          // 0..1  (M rows of waves)
    const int wc   = w & 3;           // 0..3  (N cols of waves)

    // XCD-aware bijective block swizzle (m204)
    const int nwg = gridDim.x;
    const int bid = blockIdx.x;
    const int q8 = nwg >> 3, r8 = nwg & 7;
    const int xcd = bid & 7, idx = bid >> 3;
    const int swz = (xcd < r8 ? xcd * (q8 + 1) : r8 * (q8 + 1) + (xcd - r8) * q8) + idx;
    const int nbx = N / BN;
    const int bx = swz % nbx, by = swz / nbx;

    // staging source addressing (pre-swizzled k-slot so LDS dest is linear)
    const int rowq  = t >> 3;                          // 0..63
    const int kslot = ((t & 7) ^ (rowq & 7)) << 3;     // xor'd 8-elem slot
    const bf16_t* gA = A + (size_t)(by * BM + rowq) * K + kslot;
    const bf16_t* gB = B + (size_t)(bx * BN + rowq) * K + kslot;

#define STAGE(isB, bufi, h, kt)                                                \
    do {                                                                       \
        const bf16_t* s_ = ((isB) ? gB : gA)                                   \
            + (size_t)(h) * 128 * (size_t)K + (size_t)(kt) * BK;               \
        GLL16(s_,                   &lds[bufi][isB][h][t * 8]);                \
        GLL16(s_ + 64 * (size_t)K,  &lds[bufi][isB][h][t * 8 + 4096]);         \
    } while (0)

    // ds_read addressing: frag row r = R*16 + (lane&15); k-slot (s*4+lane>>4)
    // XOR'd with (r&7) == (lane&7). aoff folds (lane&15)*64 + swizzled slot*8.
    const int l15  = lane & 15;
    const int koff = lane >> 4;                        // 0..3
    const int aoff0 = l15 * 64 + (((koff)     ^ (lane & 7)) << 3);
    const int aoff1 = l15 * 64 + (((4 + koff) ^ (lane & 7)) << 3);

    f32x4 acc[8][4];
    const f32x4 zero = {0.f, 0.f, 0.f, 0.f};
#pragma unroll
    for (int R = 0; R < 8; ++R)
#pragma unroll
        for (int Cf = 0; Cf < 4; ++Cf) acc[R][Cf] = zero;

    const int NT = K / BK;             // must be even (K % 128 == 0)

    // prologue: stage tiles 0,1; wait; read tile0's A0 + b01 fragments
    STAGE(1, 0, 0, 0); STAGE(1, 0, 1, 0);
    STAGE(0, 0, 0, 0); STAGE(0, 0, 1, 0);
    STAGE(1, 1, 0, 1); STAGE(1, 1, 1, 1);
    STAGE(0, 1, 0, 1); STAGE(0, 1, 1, 1);
    WAIT_VM0();
    SBAR();
    SCHED0();

    bf16x8 a0[4][2], a0x[4][2], a1[4][2], b01[2][2], b01x[2][2], bB[2][2];

    {
        const bf16_t* ldsA0_ = &lds[0][0][wr][0];
        const bf16_t* ldsB0_ = &lds[0][1][wc >> 1][(wc & 1) * 4096];
#pragma unroll
        for (int c = 0; c < 2; ++c) {
            b01[c][0] = *(const bf16x8*)(ldsB0_ + c * 1024 + aoff0);
            b01[c][1] = *(const bf16x8*)(ldsB0_ + c * 1024 + aoff1);
        }
#pragma unroll
        for (int R = 0; R < 4; ++R) {
            a0[R][0] = *(const bf16x8*)(ldsA0_ + R * 1024 + aoff0);
            a0[R][1] = *(const bf16x8*)(ldsA0_ + R * 1024 + aoff1);
        }
    }

#define KTILE(CUR, A0, B01, A0N, B01N, KTV)                                    \
    do {                                                                       \
        const bf16_t* ldsAc_ = &lds[CUR][0][wr][0];                            \
        const bf16_t* ldsBc_ = &lds[CUR][1][wc >> 1][(wc & 1) * 4096];         \
        const bf16_t* ldsAn_ = &lds[(CUR) ^ 1][0][wr][0];                      \
        const bf16_t* ldsBn_ = &lds[(CUR) ^ 1][1][wc >> 1][(wc & 1) * 4096];   \
        /* ---- W1: read b23,a1 of tile KTV; MFMA Q1 on prev-window regs */    \
        _Pragma("unroll")                                                      \
        for (int c = 0; c < 2; ++c) {                                          \
            bB[c][0] = *(const bf16x8*)(ldsBc_ + (2 + c) * 1024 + aoff0);      \
            bB[c][1] = *(const bf16x8*)(ldsBc_ + (2 + c) * 1024 + aoff1);      \
        }                                                                      \
        _Pragma("unroll")                                                      \
        for (int R = 0; R < 4; ++R) {                                          \
            a1[R][0] = *(const bf16x8*)(ldsAc_ + (4 + R) * 1024 + aoff0);      \
            a1[R][1] = *(const bf16x8*)(ldsAc_ + (4 + R) * 1024 + aoff1);      \
        }                                                                      \
        __builtin_amdgcn_s_setprio(1);                                         \
        _Pragma("unroll")                                                      \
        for (int s = 0; s < 2; ++s)                                            \
            _Pragma("unroll")                                                  \
            for (int R = 0; R < 4; ++R) {                                      \
                MFMA_(acc[R][0], A0[R][s], B01[0][s]);                         \
                MFMA_(acc[R][1], A0[R][s], B01[1][s]);                         \
            }                                                                  \
        __builtin_amdgcn_s_setprio(0);                                         \
        /* ---- single barrier: tile KTV+1 resident; buf[CUR] free to stage */ \
        SCHED0();                                                              \
        WAIT_VM0();                                                            \
        SBAR();                                                                \
        SCHED0();                                                              \
        /* ---- W2: pure MFMA Q2+Q3 */                                         \
        __builtin_amdgcn_s_setprio(1);                                         \
        _Pragma("unroll")                                                      \
        for (int s = 0; s < 2; ++s)                                            \
            _Pragma("unroll")                                                  \
            for (int R = 0; R < 4; ++R) {                                      \
                MFMA_(acc[R][2], A0[R][s], bB[0][s]);                          \
                MFMA_(acc[R][3], A0[R][s], bB[1][s]);                          \
            }                                                                  \
        _Pragma("unroll")                                                      \
        for (int s = 0; s < 2; ++s)                                            \
            _Pragma("unroll")                                                  \
            for (int R = 0; R < 4; ++R) {                                      \
                MFMA_(acc[4 + R][2], a1[R][s], bB[0][s]);                      \
                MFMA_(acc[4 + R][3], a1[R][s], bB[1][s]);                      \
            }                                                                  \
        __builtin_amdgcn_s_setprio(0);                                         \
        /* ---- W3: read next tile's A0,b01; stage tile KTV+2; MFMA Q4 */      \
        if ((KTV) + 1 < NT) {                                                  \
            _Pragma("unroll")                                                  \
            for (int c = 0; c < 2; ++c) {                                      \
                B01N[c][0] = *(const bf16x8*)(ldsBn_ + c * 1024 + aoff0);      \
                B01N[c][1] = *(const bf16x8*)(ldsBn_ + c * 1024 + aoff1);      \
            }                                                                  \
            _Pragma("unroll")                                                  \
            for (int R = 0; R < 4; ++R) {                                      \
                A0N[R][0] = *(const bf16x8*)(ldsAn_ + R * 1024 + aoff0);       \
                A0N[R][1] = *(const bf16x8*)(ldsAn_ + R * 1024 + aoff1);       \
            }                                                                  \
        }                                                                      \
        if ((KTV) + 2 < NT) {                                                  \
            STAGE(1, CUR, 0, (KTV) + 2); STAGE(1, CUR, 1, (KTV) + 2);          \
            STAGE(0, CUR, 0, (KTV) + 2); STAGE(0, CUR, 1, (KTV) + 2);          \
        }                                                                      \
        __builtin_amdgcn_s_setprio(1);                                         \
        _Pragma("unroll")                                                      \
        for (int s = 0; s < 2; ++s)                                            \
            _Pragma("unroll")                                                  \
            for (int R = 0; R < 4; ++R) {                                      \
                MFMA_(acc[4 + R][0], a1[R][s], B01[0][s]);                     \
                MFMA_(acc[4 + R][1], a1[R][s], B01[1][s]);                     \
            }                                                                  \
        __builtin_amdgcn_s_setprio(0);                                         \
    } while (0)

    for (int kt = 0; kt < NT; kt += 2) {
        KTILE(0, a0, b01, a0x, b01x, kt);
        KTILE(1, a0x, b01x, a0, b01, kt + 1);
    }

    // epilogue: D[row=(lane>>4)*4+j, col=lane&15] per 16x16 fragment
    const int r0 = by * BM + wr * 128 + (lane >> 4) * 4;
    const int c0 = bx * BN + wc * 64 + l15;
#pragma unroll
    for (int Cf = 0; Cf < 4; ++Cf) {
        const int col = c0 + Cf * 16;
        const float sc = scale[col];
        const float bi = bias[col];
#pragma unroll
        for (int R = 0; R < 8; ++R) {
            const int row = r0 + R * 16;
#pragma unroll
            for (int j = 0; j < 4; ++j)
                C[(size_t)(row + j) * N + col] = acc[R][Cf][j] * sc + bi;
        }
    }
#undef KTILE
#undef STAGE
}

// ---------------- launch ----------------

extern "C" void kernel_launch(void* const* d_in, const int* in_sizes, int n_in,
                              void* d_out, int out_size, void* d_ws, size_t ws_size,
                              hipStream_t stream)
{
    const float* x    = (const float*)d_in[0];
    const float* wgt  = (const float*)d_in[1];
    const float* bias = (const float*)d_in[2];

    const int OUT = in_sizes[2];
    const int IN  = (int)((long long)in_sizes[1] / OUT);
    const int M   = (int)((long long)in_sizes[0] / IN);
    const int N = OUT, K = IN;

    double ad = (double)OUT / 10000.0;
    if (ad < 0.5) ad = 0.5;
    if (ad > 2.0) ad = 2.0;
    const double sfd = 60.0 * ad;      // = 30.0 for OUT=4096

    bf16_t* Q  = (bf16_t*)d_ws;
    bf16_t* Xb = (bf16_t*)((char*)d_ws + (size_t)OUT * IN * sizeof(bf16_t));
    float*  sc = (float*)((char*)d_ws + (size_t)OUT * IN * sizeof(bf16_t)
                                      + (size_t)M * IN * sizeof(bf16_t));
    float*  C  = (float*)d_out;

    long long n8 = (long long)M * IN / 8;
    const int CB = 2048;
    prep_kernel<<<OUT + CB, 256, 0, stream>>>(wgt, Q, sc, IN, sfd,
                                              x, Xb, n8, OUT, CB);

    int grid = (M / BM) * (N / BN);
    gemm_kernel<<<grid, 512, 0, stream>>>(Xb, Q, sc, bias, C, M, N, K);
}

// Round 7
// 158.174 us; speedup vs baseline: 6.2598x; 6.2598x over previous
//
#include <hip/hip_runtime.h>
#include <hip/hip_bf16.h>

typedef __bf16 bf16_t;
typedef __bf16 bf16x8 __attribute__((ext_vector_type(8)));
typedef float f32x4 __attribute__((ext_vector_type(4)));

// async global->LDS, 16B per lane, dest = wave-uniform base + lane*16
#define GLL16(gp, lp)                                                          \
    __builtin_amdgcn_global_load_lds(                                          \
        (const __attribute__((address_space(1))) void*)(gp),                   \
        (__attribute__((address_space(3))) void*)(lp), 16, 0, 0)

#define SBAR() __builtin_amdgcn_s_barrier()
#define SCHED0() __builtin_amdgcn_sched_barrier(0)
#define WAIT_VM8() asm volatile("s_waitcnt vmcnt(8)" ::: "memory")
#define WAIT_VM0() asm volatile("s_waitcnt vmcnt(0)" ::: "memory")
#define WAIT_LGKM0() asm volatile("s_waitcnt lgkmcnt(0)" ::: "memory")
#define MFMA_(d, a, b)                                                         \
    d = __builtin_amdgcn_mfma_f32_16x16x32_bf16(a, b, d, 0, 0, 0)

// ---------------- E8 lattice quantization (fp64 decisions) ----------------

__device__ __forceinline__ void nearest_D8_d(const double x[8], double f[8]) {
    double d[8];
    double fs = 0.0;
#pragma unroll
    for (int i = 0; i < 8; ++i) {
        f[i] = rint(x[i]);              // round-half-to-even == jnp.round
        d[i] = x[i] - f[i];
        fs += f[i];
    }
    long long s = (long long)fs;
    if (s & 1LL) {
        int idx = 0;
        double best = fabs(d[0]);
#pragma unroll
        for (int i = 1; i < 8; ++i) {
            double a = fabs(d[i]);
            if (a > best) { best = a; idx = i; }   // strict > : first max
        }
        f[idx] += (d[idx] >= 0.0) ? 1.0 : -1.0;
    }
}

__device__ __forceinline__ void e8_quantize_d(const double x[8], float q[8]) {
    double y0[8], y1[8], xs[8];
    nearest_D8_d(x, y0);
#pragma unroll
    for (int i = 0; i < 8; ++i) xs[i] = x[i] - 0.5;
    nearest_D8_d(xs, y1);
#pragma unroll
    for (int i = 0; i < 8; ++i) y1[i] += 0.5;
    double d0 = 0.0, d1 = 0.0;
#pragma unroll
    for (int i = 0; i < 8; ++i) {
        double a = x[i] - y0[i]; d0 += a * a;
        double b = x[i] - y1[i]; d1 += b * b;
    }
    bool take0 = (d0 <= d1);
#pragma unroll
    for (int i = 0; i < 8; ++i) q[i] = (float)(take0 ? y0[i] : y1[i]);
}

// fused: blocks [0,OUT) quantize weight rows; blocks [OUT, OUT+CB) cvt x->bf16
__global__ __launch_bounds__(256) void prep_kernel(
    const float* __restrict__ W, bf16_t* __restrict__ Q,
    float* __restrict__ scale, int IN, double sfd,
    const float* __restrict__ x, bf16_t* __restrict__ Xb, long long n8,
    int OUT, int CB)
{
    if (blockIdx.x >= (unsigned)OUT) {
        // ---- cvt part ----
        long long i = (long long)(blockIdx.x - OUT) * 256 + threadIdx.x;
        long long stride = (long long)CB * 256;
        for (; i < n8; i += stride) {
            float4 v0 = *(const float4*)(x + i * 8);
            float4 v1 = *(const float4*)(x + i * 8 + 4);
            bf16x8 o;
            o[0] = (bf16_t)v0.x; o[1] = (bf16_t)v0.y;
            o[2] = (bf16_t)v0.z; o[3] = (bf16_t)v0.w;
            o[4] = (bf16_t)v1.x; o[5] = (bf16_t)v1.y;
            o[6] = (bf16_t)v1.z; o[7] = (bf16_t)v1.w;
            *(bf16x8*)(Xb + i * 8) = o;
        }
        return;
    }
    // ---- quant part ----
    const int row  = blockIdx.x;
    const int t    = threadIdx.x;
    const int lane = t & 63, w = t >> 6;
    const float* wrow = W + (size_t)row * IN;

    double ss = 0.0;
    for (int i = t; i < (IN >> 2); i += 256) {
        float4 v = *(const float4*)(wrow + i * 4);
        double a = v.x, b = v.y, c = v.z, d = v.w;
        ss += a * a + b * b + c * c + d * d;
    }
#pragma unroll
    for (int m = 1; m < 64; m <<= 1) ss += __shfl_xor(ss, m);
    __shared__ double red[4];
    if (lane == 0) red[w] = ss;
    __syncthreads();
    double S   = (red[0] + red[1]) + (red[2] + red[3]);
    double nsd = fmax(sqrt(S), 1e-8);

    for (int b = t; b < (IN >> 3); b += 256) {
        const float* xp = wrow + b * 8;
        float4 v0 = *(const float4*)xp;
        float4 v1 = *(const float4*)(xp + 4);
        double xd[8] = {v0.x, v0.y, v0.z, v0.w, v1.x, v1.y, v1.z, v1.w};
        double xsd[8];
#pragma unroll
        for (int i = 0; i < 8; ++i) xsd[i] = (xd[i] / nsd) * sfd;
        float qf[8];
        e8_quantize_d(xsd, qf);
        bf16x8 o;
#pragma unroll
        for (int i = 0; i < 8; ++i) o[i] = (bf16_t)qf[i];
        *(bf16x8*)(Q + (size_t)row * IN + b * 8) = o;
    }
    if (t == 0) scale[row] = (float)(nsd / sfd);
}

// ---------------- GEMM: 256x256 tile, BK=64, 8 waves.
// Slot-pipelined 2-barrier K-tile: fragments double-buffered at K=32 (slot)
// granularity (96 VGPR), so each window's MFMAs consume reads issued one
// window earlier.  W1{read slot1 | MFMA slot0 x32} lgkm0+BAR
// W2{stage kt+2 | MFMA slot1 c01 x16} vmcnt(8)+BAR  (barrier makes per-wave
// vmcnt collective -> kt+1 resident)  W3{read slot0(kt+1) from other buf |
// MFMA slot1 c23 x16} -> flows barrier-free into next W1.
// C[m,n] = (sum_k A[m,k]*B[n,k]) * scale[n] + bias[n]

#define BM 256
#define BN 256
#define BK 64

__global__ __launch_bounds__(512, 2) void gemm_kernel(
    const bf16_t* __restrict__ A,      // [M][K]
    const bf16_t* __restrict__ B,      // [N][K]
    const float* __restrict__ scale,   // [N]
    const float* __restrict__ bias,    // [N]
    float* __restrict__ C,             // [M][N]
    int M, int N, int K)
{
    // [buf][A=0/B=1][half][128 rows * 64 cols]  = 128 KiB
    __shared__ __align__(16) bf16_t lds[2][2][2][8192];

    const int t    = threadIdx.x;
    const int lane = t & 63;
    const int w    = t >> 6;          // 0..7
    const int wr   = w >> 2;          // 0..1  (M rows of waves)
    const int wc   = w & 3;           // 0..3  (N cols of waves)

    // XCD-aware bijective block swizzle (m204)
    const int nwg = gridDim.x;
    const int bid = blockIdx.x;
    const int q8 = nwg >> 3, r8 = nwg & 7;
    const int xcd = bid & 7, idx = bid >> 3;
    const int swz = (xcd < r8 ? xcd * (q8 + 1) : r8 * (q8 + 1) + (xcd - r8) * q8) + idx;
    const int nbx = N / BN;
    const int bx = swz % nbx, by = swz / nbx;

    // staging source addressing (pre-swizzled k-slot so LDS dest is linear)
    const int rowq  = t >> 3;                          // 0..63
    const int kslot = ((t & 7) ^ (rowq & 7)) << 3;     // xor'd 8-elem slot
    const bf16_t* gA = A + (size_t)(by * BM + rowq) * K + kslot;
    const bf16_t* gB = B + (size_t)(bx * BN + rowq) * K + kslot;

#define STAGE(isB, bufi, h, kt)                                                \
    do {                                                                       \
        const bf16_t* s_ = ((isB) ? gB : gA)                                   \
            + (size_t)(h) * 128 * (size_t)K + (size_t)(kt) * BK;               \
        GLL16(s_,                   &lds[bufi][isB][h][t * 8]);                \
        GLL16(s_ + 64 * (size_t)K,  &lds[bufi][isB][h][t * 8 + 4096]);         \
    } while (0)

    // ds_read addressing: frag row r = R*16 + (lane&15); k-slot (s*4+lane>>4)
    // XOR'd with (r&7) == (lane&7). aoff folds (lane&15)*64 + swizzled slot*8.
    const int l15  = lane & 15;
    const int koff = lane >> 4;                        // 0..3
    const int aoff0 = l15 * 64 + (((koff)     ^ (lane & 7)) << 3);
    const int aoff1 = l15 * 64 + (((4 + koff) ^ (lane & 7)) << 3);

    f32x4 acc[8][4];
    const f32x4 zero = {0.f, 0.f, 0.f, 0.f};
#pragma unroll
    for (int R = 0; R < 8; ++R)
#pragma unroll
        for (int Cf = 0; Cf < 4; ++Cf) acc[R][Cf] = zero;

    const int NT = K / BK;

    // prologue: stage tiles 0,1; vmcnt(8) -> tile0 resident; read slot0(t0)
    STAGE(1, 0, 0, 0); STAGE(1, 0, 1, 0);
    STAGE(0, 0, 0, 0); STAGE(0, 0, 1, 0);
    STAGE(1, 1, 0, 1); STAGE(1, 1, 1, 1);
    STAGE(0, 1, 0, 1); STAGE(0, 1, 1, 1);
    WAIT_VM8();
    SBAR();
    SCHED0();

    bf16x8 fA0[8], fA1[8], fB0[4], fB1[4];

    {
        const bf16_t* ldsA0 = &lds[0][0][wr][0];
        const bf16_t* ldsB0 = &lds[0][1][wc >> 1][(wc & 1) * 4096];
#pragma unroll
        for (int R = 0; R < 8; ++R)
            fA0[R] = *(const bf16x8*)(ldsA0 + R * 1024 + aoff0);
#pragma unroll
        for (int c = 0; c < 4; ++c)
            fB0[c] = *(const bf16x8*)(ldsB0 + c * 1024 + aoff0);
    }

    for (int kt = 0; kt < NT; ++kt) {
        const int cur = kt & 1;
        const bf16_t* ldsAc = &lds[cur][0][wr][0];
        const bf16_t* ldsBc = &lds[cur][1][wc >> 1][(wc & 1) * 4096];
        const bf16_t* ldsAn = &lds[cur ^ 1][0][wr][0];
        const bf16_t* ldsBn = &lds[cur ^ 1][1][wc >> 1][(wc & 1) * 4096];

        // ==== W1: read slot1(kt); MFMA slot0 (32, frags from last W3) ====
#pragma unroll
        for (int R = 0; R < 8; ++R)
            fA1[R] = *(const bf16x8*)(ldsAc + R * 1024 + aoff1);
#pragma unroll
        for (int c = 0; c < 4; ++c)
            fB1[c] = *(const bf16x8*)(ldsBc + c * 1024 + aoff1);
        __builtin_amdgcn_s_setprio(1);
#pragma unroll
        for (int R = 0; R < 8; ++R)
#pragma unroll
            for (int c = 0; c < 4; ++c)
                MFMA_(acc[R][c], fA0[R], fB0[c]);
        __builtin_amdgcn_s_setprio(0);
        SCHED0();
        WAIT_LGKM0();      // all my LDS reads of buf[cur] drained
        SBAR();            // -> collectively: buf[cur] free to restage
        SCHED0();

        // ==== W2: stage kt+2 into buf[cur]; MFMA slot1 cols 0-1 (16) ====
        if (kt + 2 < NT) {
            STAGE(1, cur, 0, kt + 2); STAGE(1, cur, 1, kt + 2);
            STAGE(0, cur, 0, kt + 2); STAGE(0, cur, 1, kt + 2);
        }
        __builtin_amdgcn_s_setprio(1);
#pragma unroll
        for (int R = 0; R < 8; ++R) {
            MFMA_(acc[R][0], fA1[R], fB1[0]);
            MFMA_(acc[R][1], fA1[R], fB1[1]);
        }
        __builtin_amdgcn_s_setprio(0);
        SCHED0();
        if (kt < NT - 2) { WAIT_VM8(); }       // my kt+1 loads landed
        else if (kt == NT - 2) { WAIT_VM0(); }
        SBAR();            // -> collectively: tile kt+1 resident
        SCHED0();

        // ==== W3: read slot0(kt+1) from buf[nxt]; MFMA slot1 cols 2-3 ====
        if (kt + 1 < NT) {
#pragma unroll
            for (int R = 0; R < 8; ++R)
                fA0[R] = *(const bf16x8*)(ldsAn + R * 1024 + aoff0);
#pragma unroll
            for (int c = 0; c < 4; ++c)
                fB0[c] = *(const bf16x8*)(ldsBn + c * 1024 + aoff0);
        }
        __builtin_amdgcn_s_setprio(1);
#pragma unroll
        for (int R = 0; R < 8; ++R) {
            MFMA_(acc[R][2], fA1[R], fB1[2]);
            MFMA_(acc[R][3], fA1[R], fB1[3]);
        }
        __builtin_amdgcn_s_setprio(0);
        // no barrier: W3 flows into next W1 (per-wave lgkm deps only)
    }

    // epilogue: D[row=(lane>>4)*4+j, col=lane&15] per 16x16 fragment
    const int r0 = by * BM + wr * 128 + (lane >> 4) * 4;
    const int c0 = bx * BN + wc * 64 + l15;
#pragma unroll
    for (int Cf = 0; Cf < 4; ++Cf) {
        const int col = c0 + Cf * 16;
        const float sc = scale[col];
        const float bi = bias[col];
#pragma unroll
        for (int R = 0; R < 8; ++R) {
            const int row = r0 + R * 16;
#pragma unroll
            for (int j = 0; j < 4; ++j)
                C[(size_t)(row + j) * N + col] = acc[R][Cf][j] * sc + bi;
        }
    }
#undef STAGE
}

// ---------------- launch ----------------

extern "C" void kernel_launch(void* const* d_in, const int* in_sizes, int n_in,
                              void* d_out, int out_size, void* d_ws, size_t ws_size,
                              hipStream_t stream)
{
    const float* x    = (const float*)d_in[0];
    const float* wgt  = (const float*)d_in[1];
    const float* bias = (const float*)d_in[2];

    const int OUT = in_sizes[2];
    const int IN  = (int)((long long)in_sizes[1] / OUT);
    const int M   = (int)((long long)in_sizes[0] / IN);
    const int N = OUT, K = IN;

    double ad = (double)OUT / 10000.0;
    if (ad < 0.5) ad = 0.5;
    if (ad > 2.0) ad = 2.0;
    const double sfd = 60.0 * ad;      // = 30.0 for OUT=4096

    bf16_t* Q  = (bf16_t*)d_ws;
    bf16_t* Xb = (bf16_t*)((char*)d_ws + (size_t)OUT * IN * sizeof(bf16_t));
    float*  sc = (float*)((char*)d_ws + (size_t)OUT * IN * sizeof(bf16_t)
                                      + (size_t)M * IN * sizeof(bf16_t));
    float*  C  = (float*)d_out;

    long long n8 = (long long)M * IN / 8;
    const int CB = 2048;
    prep_kernel<<<OUT + CB, 256, 0, stream>>>(wgt, Q, sc, IN, sfd,
                                              x, Xb, n8, OUT, CB);

    int grid = (M / BM) * (N / BN);
    gemm_kernel<<<grid, 512, 0, stream>>>(Xb, Q, sc, bias, C, M, N, K);
}